// Round 11
// baseline (10944.298 us; speedup 1.0000x reference)
//
#include <hip/hip_runtime.h>
#include <math.h>

#define HH   1080
#define WW   1920
#define NPIX (HH*WW)          // 2073600 < 2^21
#define MAXP 2048
#define NTHR 512
#define NWAVE (NTHR/64)       // 8
#define PPB  8192             // points per block (contiguous slab) = NTHR*KPT
#define KPT  16
#define NBLK 254              // 254*8192 >= NPIX; block 253: 1024 real pts (2/thread)

#define CXF 960.0f
#define CYF 540.0f
#define FXF 1050.0f
#define FYF 1050.0f

// 53-bit sentinel slots: (dist_bits << 21) | (0x1FFFFF - idx). 0 == "not yet".
// (zeroed each call by zero_ws_kernel)
__device__ unsigned long long g_packed[MAXP * NBLK];

__device__ __forceinline__ float proj_x(float u, float d) {
    return __fdiv_rn(__fmul_rn(__fsub_rn(u, CXF), d), FXF);
}
__device__ __forceinline__ float proj_y(float v, float d) {
    return __fdiv_rn(__fmul_rn(__fsub_rn(v, CYF), d), FYF);
}
__device__ __forceinline__ unsigned long long umax64(unsigned long long a, unsigned long long b) {
    return a > b ? a : b;
}

__global__ void zero_ws_kernel() {
    unsigned i = blockIdx.x * 256u + threadIdx.x;
    if (i < (unsigned)(MAXP * NBLK)) g_packed[i] = 0ull;
}

// ---- mutable state (running min-dists): 16 named loop-carried registers ----
#define FOR16(M)  M(0) M(1) M(2) M(3) M(4) M(5) M(6) M(7) M(8) M(9) M(10) M(11) M(12) M(13) M(14) M(15)
#define FOR16D(M) M(15) M(14) M(13) M(12) M(11) M(10) M(9) M(8) M(7) M(6) M(5) M(4) M(3) M(2) M(1) M(0)
#define DECLD(j) float D##j;

// descending j + ">=" keeps the LOWEST global index on ties (np.argmax semantics).
// Pads carry D=-1 and are scanned first; every thread owns >=2 real points,
// so bestd >= 0 always and a pad can never win.
#define UPDJ(j) { \
    unsigned o = tid + j##u * (unsigned)NTHR; \
    float4 P = sP[o]; \
    float dx = __fsub_rn(P.x, px); \
    float dy = __fsub_rn(P.y, py); \
    float dz = __fsub_rn(P.z, pz); \
    float s  = __fadd_rn(__fadd_rn(__fmul_rn(dx, dx), __fmul_rn(dy, dy)), __fmul_rn(dz, dz)); \
    float nd = fminf(D##j, s); \
    D##j = nd; \
    if (nd >= bestd) { bestd = nd; besti = base + o; } }

__global__ __attribute__((amdgpu_flat_work_group_size(NTHR, NTHR)))
void fps_kernel(const float* __restrict__ depth, const float* __restrict__ rgb,
                float* __restrict__ out)
{
    const unsigned tid  = threadIdx.x;
    const unsigned lane = threadIdx.x & 63u;
    const unsigned wid  = threadIdx.x >> 6;
    const unsigned blk  = blockIdx.x;
    const unsigned base = blk << 13;            // first pixel owned by this block
    const float FINF = __int_as_float(0x7f800000);

    __shared__ float4 sP[PPB];                  // 128 KB immutable xyz
    __shared__ unsigned long long s_pp[NWAVE];
    __shared__ unsigned           s_widx[MAXP]; // block 0 only: selected indices

    FOR16(DECLD)

    // ---- init: project owned pixels into LDS (coalesced depth loads) ----
    #define INITJ(j) { \
        unsigned o   = tid + j##u * (unsigned)NTHR; \
        unsigned idx = base + o; \
        float x, y, z; \
        if (idx < NPIX) { \
            float d = depth[idx]; \
            float u = (float)(idx % WW); \
            float v = (float)(idx / WW); \
            bool val = (d > 0.1f) && (d < 2.0f) && __builtin_isfinite(d); \
            x = val ? proj_x(u, d) : FINF; \
            y = val ? proj_y(v, d) : FINF; \
            z = val ? d : FINF; \
            D##j = FINF; \
        } else { x = 0.f; y = 0.f; z = 0.f; D##j = -1.0f; } \
        sP[o] = make_float4(x, y, z, 0.0f); }
    FOR16(INITJ)

    if (tid == 0) s_widx[0] = 0u;
    __syncthreads();   // LDS xyz visible to all waves before iterating

    // first FPS point = flat index 0
    float px, py, pz;
    {
        float d = depth[0];
        bool val = (d > 0.1f) && (d < 2.0f) && __builtin_isfinite(d);
        px = val ? proj_x(0.0f, d) : FINF;
        py = val ? proj_y(0.0f, d) : FINF;
        pz = val ? d : FINF;
    }

    // lanes 0..61 also poll slot lane+192 (254 slots total)
    const bool has3 = (lane + 192u) < (unsigned)NBLK;

    for (int it = 1; it < MAXP; ++it) {
        // ---- distance update (LDS xyz + register D) + thread-local argmax ----
        float bestd = -2.0f;
        unsigned besti = 0u;
        FOR16D(UPDJ)

        // 53-bit pack: never 0 for a real candidate (besti < NPIX < 0x1FFFFF)
        unsigned long long pk =
            ((unsigned long long)__float_as_uint(bestd) << 21) |
            (unsigned long long)(0x1FFFFFu - besti);

        // ---- wave reduce (u64 max) ----
        #pragma unroll
        for (int off = 32; off; off >>= 1) pk = umax64(pk, __shfl_xor(pk, off));
        if (lane == 0) s_pp[wid] = pk;
        __syncthreads();   // the ONLY barrier in the loop

        // ---- wave 0: block reduce + relaxed write-through store (no fences) ----
        if (wid == 0 && lane == 0) {
            unsigned long long p2 = s_pp[0];
            #pragma unroll
            for (int k = 1; k < NWAVE; ++k) p2 = umax64(p2, s_pp[k]);
            __hip_atomic_store(&g_packed[(size_t)it * NBLK + blk], p2,
                               __ATOMIC_RELAXED, __HIP_MEMORY_SCOPE_AGENT);
        }

        // ---- EVERY wave polls all 254 slots (4/lane, one round trip per retry) ----
        const unsigned long long* row = &g_packed[(size_t)it * NBLK];
        unsigned long long v0, v1, v2, v3 = 0ull;
        for (;;) {
            v0 = __hip_atomic_load(row + lane,        __ATOMIC_RELAXED, __HIP_MEMORY_SCOPE_AGENT);
            v1 = __hip_atomic_load(row + lane + 64u,  __ATOMIC_RELAXED, __HIP_MEMORY_SCOPE_AGENT);
            v2 = __hip_atomic_load(row + lane + 128u, __ATOMIC_RELAXED, __HIP_MEMORY_SCOPE_AGENT);
            if (has3)
                v3 = __hip_atomic_load(row + lane + 192u, __ATOMIC_RELAXED, __HIP_MEMORY_SCOPE_AGENT);
            if (v0 != 0ull && v1 != 0ull && v2 != 0ull && (!has3 || v3 != 0ull)) break;
            __builtin_amdgcn_s_sleep(1);
        }
        unsigned long long w = umax64(umax64(v0, v1), umax64(v2, v3));
        #pragma unroll
        for (int off = 32; off; off >>= 1) w = umax64(w, __shfl_xor(w, off));

        // ---- winner known per-wave: no barrier, per-wave depth broadcast ----
        unsigned widx = 0x1FFFFFu - (unsigned)(w & 0x1FFFFFull);
        if (blk == 0 && wid == 0 && lane == 0) s_widx[it] = widx;
        float wd = 0.0f;
        if (lane == 0) wd = depth[widx];
        wd = __shfl(wd, 0);

        float uu = (float)(widx % WW);
        float vv = (float)(widx / WW);
        bool val = (wd > 0.1f) && (wd < 2.0f) && __builtin_isfinite(wd);
        px = val ? proj_x(uu, wd) : FINF;
        py = val ? proj_y(vv, wd) : FINF;
        pz = val ? wd : FINF;
    }

    // ---- epilogue: block 0 gathers, normalizes, writes [2048,9] ----
    if (blk == 0) {
        __syncthreads();   // wave 0's s_widx writes visible to all waves
        float ex[4], ey[4], ez[4], er[4], eg[4], eb[4];
        #pragma unroll
        for (int q = 0; q < 4; ++q) {
            int i = (int)tid + q * NTHR;
            unsigned sidx = s_widx[i];
            float d = depth[sidx];
            float u = (float)(sidx % WW);
            float v = (float)(sidx / WW);
            bool val = (d > 0.1f) && (d < 2.0f) && __builtin_isfinite(d);
            ex[q] = val ? proj_x(u, d) : FINF;
            ey[q] = val ? proj_y(v, d) : FINF;
            ez[q] = val ? d : FINF;
            er[q] = val ? __fdiv_rn(rgb[3u * sidx + 0u], 255.0f) : 0.0f;
            eg[q] = val ? __fdiv_rn(rgb[3u * sidx + 1u], 255.0f) : 0.0f;
            eb[q] = val ? __fdiv_rn(rgb[3u * sidx + 2u], 255.0f) : 0.0f;
        }
        float mn[3], mx[3];
        mn[0] = fminf(fminf(ex[0], ex[1]), fminf(ex[2], ex[3]));
        mx[0] = fmaxf(fmaxf(ex[0], ex[1]), fmaxf(ex[2], ex[3]));
        mn[1] = fminf(fminf(ey[0], ey[1]), fminf(ey[2], ey[3]));
        mx[1] = fmaxf(fmaxf(ey[0], ey[1]), fmaxf(ey[2], ey[3]));
        mn[2] = fminf(fminf(ez[0], ez[1]), fminf(ez[2], ez[3]));
        mx[2] = fmaxf(fmaxf(ez[0], ez[1]), fmaxf(ez[2], ez[3]));
        #pragma unroll
        for (int c = 0; c < 3; ++c) {
            for (int off = 32; off > 0; off >>= 1) {
                mn[c] = fminf(mn[c], __shfl_xor(mn[c], off));
                mx[c] = fmaxf(mx[c], __shfl_xor(mx[c], off));
            }
        }
        __shared__ float s_mn[NWAVE][3], s_mx[NWAVE][3];
        __shared__ float f_mn[3], f_sc[3];
        if (lane == 0) {
            for (int c = 0; c < 3; ++c) { s_mn[wid][c] = mn[c]; s_mx[wid][c] = mx[c]; }
        }
        __syncthreads();
        if (wid == 0) {
            float a[3], b[3];
            for (int c = 0; c < 3; ++c) {
                a[c] = (lane < NWAVE) ? s_mn[lane][c] : FINF;
                b[c] = (lane < NWAVE) ? s_mx[lane][c] : -FINF;
            }
            for (int off = NWAVE / 2; off > 0; off >>= 1) {
                for (int c = 0; c < 3; ++c) {
                    a[c] = fminf(a[c], __shfl_xor(a[c], off));
                    b[c] = fmaxf(b[c], __shfl_xor(b[c], off));
                }
            }
            if (lane == 0) {
                for (int c = 0; c < 3; ++c) {
                    f_mn[c] = a[c];
                    float m = __fsub_rn(b[c], a[c]);   // == max(centered) by monotonicity
                    f_sc[c] = (m < 1e-8f) ? 1.0f : m;
                }
            }
        }
        __syncthreads();
        float MN0 = f_mn[0], MN1 = f_mn[1], MN2 = f_mn[2];
        float SC0 = f_sc[0], SC1 = f_sc[1], SC2 = f_sc[2];
        #pragma unroll
        for (int q = 0; q < 4; ++q) {
            int i = (int)tid + q * NTHR;
            out[9 * i + 0] = ex[q];
            out[9 * i + 1] = ey[q];
            out[9 * i + 2] = ez[q];
            out[9 * i + 3] = er[q];
            out[9 * i + 4] = eg[q];
            out[9 * i + 5] = eb[q];
            out[9 * i + 6] = __fdiv_rn(__fsub_rn(ex[q], MN0), SC0);
            out[9 * i + 7] = __fdiv_rn(__fsub_rn(ey[q], MN1), SC1);
            out[9 * i + 8] = __fdiv_rn(__fsub_rn(ez[q], MN2), SC2);
        }
    }
}

extern "C" void kernel_launch(void* const* d_in, const int* in_sizes, int n_in,
                              void* d_out, int out_size, void* d_ws, size_t ws_size,
                              hipStream_t stream) {
    const float* depth = (const float*)d_in[0];
    const float* rgb   = (const float*)d_in[1];
    float* out = (float*)d_out;

    // re-initialize communication slots (deterministic per call / per graph replay)
    zero_ws_kernel<<<dim3((MAXP * NBLK + 255) / 256), dim3(256), 0, stream>>>();

    void* args[] = { (void*)&depth, (void*)&rgb, (void*)&out };
    hipLaunchCooperativeKernel((const void*)fps_kernel, dim3(NBLK), dim3(NTHR),
                               args, 0, stream);
}

// Round 12
// 6762.397 us; speedup vs baseline: 1.6184x; 1.6184x over previous
//
#include <hip/hip_runtime.h>
#include <math.h>

#define HH   1080
#define WW   1920
#define NPIX (HH*WW)          // 2073600 < 2^21
#define MAXP 2048
#define NTHR 512
#define NWAVE (NTHR/64)       // 8
#define PPB  8192             // points per compute block = NTHR*KPT
#define KPT  16
#define NBLK 254              // compute blocks; block NBLK is the aggregator

#define CXF 960.0f
#define CYF 540.0f
#define FXF 1050.0f
#define FYF 1050.0f

// per-iteration per-block candidate slots: (dist<<21)|(0x1FFFFF-idx), 0 = not yet
__device__ unsigned long long g_packed[MAXP * NBLK];
// per-iteration winner broadcast: (depth_bits<<21)|(0x1FFFFF-widx), 0 = not yet
__device__ unsigned long long g_win[MAXP];

__device__ __forceinline__ float proj_x(float u, float d) {
    return __fdiv_rn(__fmul_rn(__fsub_rn(u, CXF), d), FXF);
}
__device__ __forceinline__ float proj_y(float v, float d) {
    return __fdiv_rn(__fmul_rn(__fsub_rn(v, CYF), d), FYF);
}
__device__ __forceinline__ unsigned long long umax64(unsigned long long a, unsigned long long b) {
    return a > b ? a : b;
}

__global__ void zero_ws_kernel() {
    unsigned i = blockIdx.x * 256u + threadIdx.x;
    if (i < (unsigned)(MAXP * NBLK)) g_packed[i] = 0ull;
    if (i < (unsigned)MAXP)          g_win[i]    = 0ull;
}

// ---- mutable state (running min-dists): 16 named loop-carried registers ----
#define FOR16(M)  M(0) M(1) M(2) M(3) M(4) M(5) M(6) M(7) M(8) M(9) M(10) M(11) M(12) M(13) M(14) M(15)
#define FOR16D(M) M(15) M(14) M(13) M(12) M(11) M(10) M(9) M(8) M(7) M(6) M(5) M(4) M(3) M(2) M(1) M(0)
#define DECLD(j) float D##j;

// descending j + ">=" keeps the LOWEST global index on ties (np.argmax semantics).
// Pads carry D=-1 and are scanned first; every thread owns >=2 real points.
#define UPDJ(j) { \
    unsigned o = tid + j##u * (unsigned)NTHR; \
    float4 P = sP[o]; \
    float dx = __fsub_rn(P.x, px); \
    float dy = __fsub_rn(P.y, py); \
    float dz = __fsub_rn(P.z, pz); \
    float s  = __fadd_rn(__fadd_rn(__fmul_rn(dx, dx), __fmul_rn(dy, dy)), __fmul_rn(dz, dz)); \
    float nd = fminf(D##j, s); \
    D##j = nd; \
    if (nd >= bestd) { bestd = nd; besti = base + o; } }

__global__ __attribute__((amdgpu_flat_work_group_size(NTHR, NTHR)))
void fps_kernel(const float* __restrict__ depth, const float* __restrict__ rgb,
                float* __restrict__ out)
{
    const unsigned tid  = threadIdx.x;
    const unsigned lane = threadIdx.x & 63u;
    const unsigned wid  = threadIdx.x >> 6;
    const unsigned blk  = blockIdx.x;
    const float FINF = __int_as_float(0x7f800000);

    __shared__ float4 sP[PPB];                  // 128 KB immutable xyz (compute blocks)
    __shared__ unsigned long long s_pp[NWAVE];
    __shared__ unsigned long long s_win;
    __shared__ unsigned           s_widx[MAXP]; // aggregator only

    // ================= AGGREGATOR BLOCK =================
    if (blk == (unsigned)NBLK) {
        if (wid == 0) {
            if (lane == 0) s_widx[0] = 0u;
            const bool has3 = (lane + 192u) < (unsigned)NBLK;
            for (int it = 1; it < MAXP; ++it) {
                const unsigned long long* row = &g_packed[(size_t)it * NBLK];
                unsigned long long v0, v1, v2, v3 = 0ull;
                for (;;) {
                    v0 = __hip_atomic_load(row + lane,        __ATOMIC_RELAXED, __HIP_MEMORY_SCOPE_AGENT);
                    v1 = __hip_atomic_load(row + lane + 64u,  __ATOMIC_RELAXED, __HIP_MEMORY_SCOPE_AGENT);
                    v2 = __hip_atomic_load(row + lane + 128u, __ATOMIC_RELAXED, __HIP_MEMORY_SCOPE_AGENT);
                    if (has3)
                        v3 = __hip_atomic_load(row + lane + 192u, __ATOMIC_RELAXED, __HIP_MEMORY_SCOPE_AGENT);
                    if (v0 != 0ull && v1 != 0ull && v2 != 0ull && (!has3 || v3 != 0ull)) break;
                    __builtin_amdgcn_s_sleep(1);
                }
                unsigned long long w = umax64(umax64(v0, v1), umax64(v2, v3));
                #pragma unroll
                for (int off = 32; off; off >>= 1) w = umax64(w, __shfl_xor(w, off));
                unsigned widx = 0x1FFFFFu - (unsigned)(w & 0x1FFFFFull);
                if (lane == 0) {
                    float wd = depth[widx];          // one LLC load, once per iteration
                    s_widx[it] = widx;
                    __hip_atomic_store(&g_win[it],
                        ((unsigned long long)__float_as_uint(wd) << 21) |
                        (unsigned long long)(0x1FFFFFu - widx),
                        __ATOMIC_RELAXED, __HIP_MEMORY_SCOPE_AGENT);
                }
            }
        }
        __syncthreads();   // waves 1-7 wait here for wave 0 to finish the loop

        // ---- epilogue: gather, normalize, write [2048,9] ----
        float ex[4], ey[4], ez[4], er[4], eg[4], eb[4];
        #pragma unroll
        for (int q = 0; q < 4; ++q) {
            int i = (int)tid + q * NTHR;
            unsigned sidx = s_widx[i];
            float d = depth[sidx];
            float u = (float)(sidx % WW);
            float v = (float)(sidx / WW);
            bool val = (d > 0.1f) && (d < 2.0f) && __builtin_isfinite(d);
            ex[q] = val ? proj_x(u, d) : FINF;
            ey[q] = val ? proj_y(v, d) : FINF;
            ez[q] = val ? d : FINF;
            er[q] = val ? __fdiv_rn(rgb[3u * sidx + 0u], 255.0f) : 0.0f;
            eg[q] = val ? __fdiv_rn(rgb[3u * sidx + 1u], 255.0f) : 0.0f;
            eb[q] = val ? __fdiv_rn(rgb[3u * sidx + 2u], 255.0f) : 0.0f;
        }
        float mn[3], mx[3];
        mn[0] = fminf(fminf(ex[0], ex[1]), fminf(ex[2], ex[3]));
        mx[0] = fmaxf(fmaxf(ex[0], ex[1]), fmaxf(ex[2], ex[3]));
        mn[1] = fminf(fminf(ey[0], ey[1]), fminf(ey[2], ey[3]));
        mx[1] = fmaxf(fmaxf(ey[0], ey[1]), fmaxf(ey[2], ey[3]));
        mn[2] = fminf(fminf(ez[0], ez[1]), fminf(ez[2], ez[3]));
        mx[2] = fmaxf(fmaxf(ez[0], ez[1]), fmaxf(ez[2], ez[3]));
        #pragma unroll
        for (int c = 0; c < 3; ++c) {
            for (int off = 32; off > 0; off >>= 1) {
                mn[c] = fminf(mn[c], __shfl_xor(mn[c], off));
                mx[c] = fmaxf(mx[c], __shfl_xor(mx[c], off));
            }
        }
        __shared__ float s_mn[NWAVE][3], s_mx[NWAVE][3];
        __shared__ float f_mn[3], f_sc[3];
        if (lane == 0) {
            for (int c = 0; c < 3; ++c) { s_mn[wid][c] = mn[c]; s_mx[wid][c] = mx[c]; }
        }
        __syncthreads();
        if (wid == 0) {
            float a[3], b[3];
            for (int c = 0; c < 3; ++c) {
                a[c] = (lane < NWAVE) ? s_mn[lane][c] : FINF;
                b[c] = (lane < NWAVE) ? s_mx[lane][c] : -FINF;
            }
            for (int off = NWAVE / 2; off > 0; off >>= 1) {
                for (int c = 0; c < 3; ++c) {
                    a[c] = fminf(a[c], __shfl_xor(a[c], off));
                    b[c] = fmaxf(b[c], __shfl_xor(b[c], off));
                }
            }
            if (lane == 0) {
                for (int c = 0; c < 3; ++c) {
                    f_mn[c] = a[c];
                    float m = __fsub_rn(b[c], a[c]);   // == max(centered) by monotonicity
                    f_sc[c] = (m < 1e-8f) ? 1.0f : m;
                }
            }
        }
        __syncthreads();
        float MN0 = f_mn[0], MN1 = f_mn[1], MN2 = f_mn[2];
        float SC0 = f_sc[0], SC1 = f_sc[1], SC2 = f_sc[2];
        #pragma unroll
        for (int q = 0; q < 4; ++q) {
            int i = (int)tid + q * NTHR;
            out[9 * i + 0] = ex[q];
            out[9 * i + 1] = ey[q];
            out[9 * i + 2] = ez[q];
            out[9 * i + 3] = er[q];
            out[9 * i + 4] = eg[q];
            out[9 * i + 5] = eb[q];
            out[9 * i + 6] = __fdiv_rn(__fsub_rn(ex[q], MN0), SC0);
            out[9 * i + 7] = __fdiv_rn(__fsub_rn(ey[q], MN1), SC1);
            out[9 * i + 8] = __fdiv_rn(__fsub_rn(ez[q], MN2), SC2);
        }
        return;
    }

    // ================= COMPUTE BLOCKS =================
    const unsigned base = blk << 13;            // first pixel owned by this block

    FOR16(DECLD)

    #define INITJ(j) { \
        unsigned o   = tid + j##u * (unsigned)NTHR; \
        unsigned idx = base + o; \
        float x, y, z; \
        if (idx < NPIX) { \
            float d = depth[idx]; \
            float u = (float)(idx % WW); \
            float v = (float)(idx / WW); \
            bool val = (d > 0.1f) && (d < 2.0f) && __builtin_isfinite(d); \
            x = val ? proj_x(u, d) : FINF; \
            y = val ? proj_y(v, d) : FINF; \
            z = val ? d : FINF; \
            D##j = FINF; \
        } else { x = 0.f; y = 0.f; z = 0.f; D##j = -1.0f; } \
        sP[o] = make_float4(x, y, z, 0.0f); }
    FOR16(INITJ)
    __syncthreads();   // LDS xyz visible to all waves before iterating

    // first FPS point = flat index 0
    float px, py, pz;
    {
        float d = depth[0];
        bool val = (d > 0.1f) && (d < 2.0f) && __builtin_isfinite(d);
        px = val ? proj_x(0.0f, d) : FINF;
        py = val ? proj_y(0.0f, d) : FINF;
        pz = val ? d : FINF;
    }

    for (int it = 1; it < MAXP; ++it) {
        // ---- distance update (LDS xyz + register D) + thread-local argmax ----
        float bestd = -2.0f;
        unsigned besti = 0u;
        FOR16D(UPDJ)

        unsigned long long pk =
            ((unsigned long long)__float_as_uint(bestd) << 21) |
            (unsigned long long)(0x1FFFFFu - besti);

        // ---- wave reduce (u64 max) ----
        #pragma unroll
        for (int off = 32; off; off >>= 1) pk = umax64(pk, __shfl_xor(pk, off));
        if (lane == 0) s_pp[wid] = pk;
        __syncthreads();   // barrier A

        if (wid == 0 && lane == 0) {
            unsigned long long p2 = s_pp[0];
            #pragma unroll
            for (int k = 1; k < NWAVE; ++k) p2 = umax64(p2, s_pp[k]);
            __hip_atomic_store(&g_packed[(size_t)it * NBLK + blk], p2,
                               __ATOMIC_RELAXED, __HIP_MEMORY_SCOPE_AGENT);
        }

        if (it == MAXP - 1) break;   // last winner not needed by compute blocks

        // ---- single-word winner detection (lane 0 of wave 0 only) ----
        if (wid == 0 && lane == 0) {
            unsigned long long gv;
            for (;;) {
                gv = __hip_atomic_load(&g_win[it], __ATOMIC_RELAXED, __HIP_MEMORY_SCOPE_AGENT);
                if (gv != 0ull) break;
            }
            s_win = gv;
        }
        __syncthreads();   // barrier B

        unsigned long long gv = s_win;
        unsigned widx = 0x1FFFFFu - (unsigned)(gv & 0x1FFFFFull);
        float    wd   = __uint_as_float((unsigned)(gv >> 21));

        float uu = (float)(widx % WW);
        float vv = (float)(widx / WW);
        bool val = (wd > 0.1f) && (wd < 2.0f) && __builtin_isfinite(wd);
        px = val ? proj_x(uu, wd) : FINF;
        py = val ? proj_y(vv, wd) : FINF;
        pz = val ? wd : FINF;
    }
}

extern "C" void kernel_launch(void* const* d_in, const int* in_sizes, int n_in,
                              void* d_out, int out_size, void* d_ws, size_t ws_size,
                              hipStream_t stream) {
    const float* depth = (const float*)d_in[0];
    const float* rgb   = (const float*)d_in[1];
    float* out = (float*)d_out;

    // re-initialize communication slots (deterministic per call / per graph replay)
    zero_ws_kernel<<<dim3((MAXP * NBLK + 255) / 256), dim3(256), 0, stream>>>();

    void* args[] = { (void*)&depth, (void*)&rgb, (void*)&out };
    hipLaunchCooperativeKernel((const void*)fps_kernel, dim3(NBLK + 1), dim3(NTHR),
                               args, 0, stream);
}

// Round 13
// 6488.152 us; speedup vs baseline: 1.6868x; 1.0423x over previous
//
#include <hip/hip_runtime.h>
#include <math.h>

#define HH   1080
#define WW   1920
#define NPIX (HH*WW)          // 2073600 < 2^21
#define MAXP 2048
#define NTHR 512
#define NWAVE (NTHR/64)       // 8
#define PPB  8192             // points per compute block = NTHR*KPT
#define KPT  16
#define NBLK 254              // compute blocks; block NBLK is the aggregator

#define CXF 960.0f
#define CYF 540.0f
#define FXF 1050.0f
#define FYF 1050.0f

// Tagged slots, parity-reused: value = (it<<53) | (dist_bits<<21) | (0x1FFFFF - idx).
// A slot is "ready for it" iff (v>>53)==it. Only 2 rows -> always cache-hot.
__device__ unsigned long long g_packed[2 * NBLK];
// winner broadcast, parity-reused: (it<<53) | (depth_bits<<21) | (0x1FFFFF - widx)
__device__ unsigned long long g_win[2];

__device__ __forceinline__ float proj_x(float u, float d) {
    return __fdiv_rn(__fmul_rn(__fsub_rn(u, CXF), d), FXF);
}
__device__ __forceinline__ float proj_y(float v, float d) {
    return __fdiv_rn(__fmul_rn(__fsub_rn(v, CYF), d), FYF);
}
__device__ __forceinline__ unsigned long long umax64(unsigned long long a, unsigned long long b) {
    return a > b ? a : b;
}

__global__ void zero_ws_kernel() {
    unsigned i = threadIdx.x;
    if (i < 2u * NBLK) g_packed[i] = 0ull;
    if (i < 2u)        g_win[i]    = 0ull;
}

// ---- mutable state (running min-dists): 16 named loop-carried registers ----
#define FOR16(M)  M(0) M(1) M(2) M(3) M(4) M(5) M(6) M(7) M(8) M(9) M(10) M(11) M(12) M(13) M(14) M(15)
#define FOR16D(M) M(15) M(14) M(13) M(12) M(11) M(10) M(9) M(8) M(7) M(6) M(5) M(4) M(3) M(2) M(1) M(0)
#define DECLD(j) float D##j;

// descending j + ">=" keeps the LOWEST global index on ties (np.argmax semantics).
// Pads carry D=-1 and are scanned first; every thread owns >=2 real points.
#define UPDJ(j) { \
    unsigned o = tid + j##u * (unsigned)NTHR; \
    float4 P = sP[o]; \
    float dx = __fsub_rn(P.x, px); \
    float dy = __fsub_rn(P.y, py); \
    float dz = __fsub_rn(P.z, pz); \
    float s  = __fadd_rn(__fadd_rn(__fmul_rn(dx, dx), __fmul_rn(dy, dy)), __fmul_rn(dz, dz)); \
    float nd = fminf(D##j, s); \
    D##j = nd; \
    if (nd >= bestd) { bestd = nd; besti = base + o; } }

__global__ __attribute__((amdgpu_flat_work_group_size(NTHR, NTHR)))
void fps_kernel(const float* __restrict__ depth, const float* __restrict__ rgb,
                float* __restrict__ out)
{
    const unsigned tid  = threadIdx.x;
    const unsigned lane = threadIdx.x & 63u;
    const unsigned wid  = threadIdx.x >> 6;
    const unsigned blk  = blockIdx.x;
    const float FINF = __int_as_float(0x7f800000);

    __shared__ float4 sP[PPB];                  // 128 KB immutable xyz (compute blocks)
    __shared__ unsigned long long s_pp[NWAVE];
    __shared__ unsigned long long s_win;        // tagged winner broadcast within block
    __shared__ unsigned           s_widx[MAXP]; // aggregator only

    // ================= AGGREGATOR BLOCK =================
    if (blk == (unsigned)NBLK) {
        if (wid == 0) {
            if (lane == 0) s_widx[0] = 0u;
            const bool has3 = (lane + 192u) < (unsigned)NBLK;
            for (int it = 1; it < MAXP; ++it) {
                const unsigned long long tag = (unsigned long long)it;
                const unsigned long long* row = &g_packed[(size_t)(it & 1) * NBLK];
                unsigned long long v0, v1, v2, v3 = 0ull;
                for (;;) {
                    v0 = __hip_atomic_load(row + lane,        __ATOMIC_RELAXED, __HIP_MEMORY_SCOPE_AGENT);
                    v1 = __hip_atomic_load(row + lane + 64u,  __ATOMIC_RELAXED, __HIP_MEMORY_SCOPE_AGENT);
                    v2 = __hip_atomic_load(row + lane + 128u, __ATOMIC_RELAXED, __HIP_MEMORY_SCOPE_AGENT);
                    if (has3)
                        v3 = __hip_atomic_load(row + lane + 192u, __ATOMIC_RELAXED, __HIP_MEMORY_SCOPE_AGENT);
                    if ((v0 >> 53) == tag && (v1 >> 53) == tag && (v2 >> 53) == tag &&
                        (!has3 || (v3 >> 53) == tag)) break;
                    __builtin_amdgcn_s_sleep(1);
                }
                // same tag on all real slots -> full-word max == max over (dist,idx)
                unsigned long long w = umax64(umax64(v0, v1), umax64(v2, v3));
                #pragma unroll
                for (int off = 32; off; off >>= 1) w = umax64(w, __shfl_xor(w, off));
                unsigned widx = 0x1FFFFFu - (unsigned)(w & 0x1FFFFFull);
                if (lane == 0) {
                    float wd = depth[widx];          // one LLC load per iteration
                    s_widx[it] = widx;
                    __hip_atomic_store(&g_win[it & 1],
                        (tag << 53) |
                        ((unsigned long long)__float_as_uint(wd) << 21) |
                        (unsigned long long)(0x1FFFFFu - widx),
                        __ATOMIC_RELAXED, __HIP_MEMORY_SCOPE_AGENT);
                }
            }
        }
        __syncthreads();   // waves 1-7 wait for wave 0 to finish the loop

        // ---- epilogue: gather, normalize, write [2048,9] ----
        float ex[4], ey[4], ez[4], er[4], eg[4], eb[4];
        #pragma unroll
        for (int q = 0; q < 4; ++q) {
            int i = (int)tid + q * NTHR;
            unsigned sidx = s_widx[i];
            float d = depth[sidx];
            float u = (float)(sidx % WW);
            float v = (float)(sidx / WW);
            bool val = (d > 0.1f) && (d < 2.0f) && __builtin_isfinite(d);
            ex[q] = val ? proj_x(u, d) : FINF;
            ey[q] = val ? proj_y(v, d) : FINF;
            ez[q] = val ? d : FINF;
            er[q] = val ? __fdiv_rn(rgb[3u * sidx + 0u], 255.0f) : 0.0f;
            eg[q] = val ? __fdiv_rn(rgb[3u * sidx + 1u], 255.0f) : 0.0f;
            eb[q] = val ? __fdiv_rn(rgb[3u * sidx + 2u], 255.0f) : 0.0f;
        }
        float mn[3], mx[3];
        mn[0] = fminf(fminf(ex[0], ex[1]), fminf(ex[2], ex[3]));
        mx[0] = fmaxf(fmaxf(ex[0], ex[1]), fmaxf(ex[2], ex[3]));
        mn[1] = fminf(fminf(ey[0], ey[1]), fminf(ey[2], ey[3]));
        mx[1] = fmaxf(fmaxf(ey[0], ey[1]), fmaxf(ey[2], ey[3]));
        mn[2] = fminf(fminf(ez[0], ez[1]), fminf(ez[2], ez[3]));
        mx[2] = fmaxf(fmaxf(ez[0], ez[1]), fmaxf(ez[2], ez[3]));
        #pragma unroll
        for (int c = 0; c < 3; ++c) {
            for (int off = 32; off > 0; off >>= 1) {
                mn[c] = fminf(mn[c], __shfl_xor(mn[c], off));
                mx[c] = fmaxf(mx[c], __shfl_xor(mx[c], off));
            }
        }
        __shared__ float s_mn[NWAVE][3], s_mx[NWAVE][3];
        __shared__ float f_mn[3], f_sc[3];
        if (lane == 0) {
            for (int c = 0; c < 3; ++c) { s_mn[wid][c] = mn[c]; s_mx[wid][c] = mx[c]; }
        }
        __syncthreads();
        if (wid == 0) {
            float a[3], b[3];
            for (int c = 0; c < 3; ++c) {
                a[c] = (lane < NWAVE) ? s_mn[lane][c] : FINF;
                b[c] = (lane < NWAVE) ? s_mx[lane][c] : -FINF;
            }
            for (int off = NWAVE / 2; off > 0; off >>= 1) {
                for (int c = 0; c < 3; ++c) {
                    a[c] = fminf(a[c], __shfl_xor(a[c], off));
                    b[c] = fmaxf(b[c], __shfl_xor(b[c], off));
                }
            }
            if (lane == 0) {
                for (int c = 0; c < 3; ++c) {
                    f_mn[c] = a[c];
                    float m = __fsub_rn(b[c], a[c]);   // == max(centered) by monotonicity
                    f_sc[c] = (m < 1e-8f) ? 1.0f : m;
                }
            }
        }
        __syncthreads();
        float MN0 = f_mn[0], MN1 = f_mn[1], MN2 = f_mn[2];
        float SC0 = f_sc[0], SC1 = f_sc[1], SC2 = f_sc[2];
        #pragma unroll
        for (int q = 0; q < 4; ++q) {
            int i = (int)tid + q * NTHR;
            out[9 * i + 0] = ex[q];
            out[9 * i + 1] = ey[q];
            out[9 * i + 2] = ez[q];
            out[9 * i + 3] = er[q];
            out[9 * i + 4] = eg[q];
            out[9 * i + 5] = eb[q];
            out[9 * i + 6] = __fdiv_rn(__fsub_rn(ex[q], MN0), SC0);
            out[9 * i + 7] = __fdiv_rn(__fsub_rn(ey[q], MN1), SC1);
            out[9 * i + 8] = __fdiv_rn(__fsub_rn(ez[q], MN2), SC2);
        }
        return;
    }

    // ================= COMPUTE BLOCKS =================
    const unsigned base = blk << 13;            // first pixel owned by this block

    FOR16(DECLD)

    #define INITJ(j) { \
        unsigned o   = tid + j##u * (unsigned)NTHR; \
        unsigned idx = base + o; \
        float x, y, z; \
        if (idx < NPIX) { \
            float d = depth[idx]; \
            float u = (float)(idx % WW); \
            float v = (float)(idx / WW); \
            bool val = (d > 0.1f) && (d < 2.0f) && __builtin_isfinite(d); \
            x = val ? proj_x(u, d) : FINF; \
            y = val ? proj_y(v, d) : FINF; \
            z = val ? d : FINF; \
            D##j = FINF; \
        } else { x = 0.f; y = 0.f; z = 0.f; D##j = -1.0f; } \
        sP[o] = make_float4(x, y, z, 0.0f); }
    FOR16(INITJ)
    if (tid == 0) s_win = 0ull;
    __syncthreads();   // LDS xyz + s_win init visible before iterating

    // first FPS point = flat index 0
    float px, py, pz;
    {
        float d = depth[0];
        bool val = (d > 0.1f) && (d < 2.0f) && __builtin_isfinite(d);
        px = val ? proj_x(0.0f, d) : FINF;
        py = val ? proj_y(0.0f, d) : FINF;
        pz = val ? d : FINF;
    }

    for (int it = 1; it < MAXP; ++it) {
        const unsigned long long tag = (unsigned long long)it;

        // ---- distance update (LDS xyz + register D) + thread-local argmax ----
        float bestd = -2.0f;
        unsigned besti = 0u;
        FOR16D(UPDJ)

        unsigned long long pk =
            (tag << 53) |
            ((unsigned long long)__float_as_uint(bestd) << 21) |
            (unsigned long long)(0x1FFFFFu - besti);

        // ---- wave reduce (u64 max; same tag everywhere) ----
        #pragma unroll
        for (int off = 32; off; off >>= 1) pk = umax64(pk, __shfl_xor(pk, off));
        if (lane == 0) s_pp[wid] = pk;
        __syncthreads();   // barrier A: s_pp complete before wave-0 reads

        if (wid == 0 && lane == 0) {
            unsigned long long p2 = s_pp[0];
            #pragma unroll
            for (int k = 1; k < NWAVE; ++k) p2 = umax64(p2, s_pp[k]);
            __hip_atomic_store(&g_packed[(size_t)(it & 1) * NBLK + blk], p2,
                               __ATOMIC_RELAXED, __HIP_MEMORY_SCOPE_AGENT);
        }

        if (it == MAXP - 1) break;   // last winner not needed by compute blocks

        // ---- wave0-lane0 spins on the single winner word, relays via LDS tag ----
        if (wid == 0 && lane == 0) {
            unsigned long long gv;
            for (;;) {
                gv = __hip_atomic_load(&g_win[it & 1], __ATOMIC_RELAXED, __HIP_MEMORY_SCOPE_AGENT);
                if ((gv >> 53) == tag) break;
            }
            __hip_atomic_store(&s_win, gv, __ATOMIC_RELAXED, __HIP_MEMORY_SCOPE_WORKGROUP);
        }
        // all threads: LDS tag spin (same-address broadcast reads, no barrier needed)
        unsigned long long gv;
        for (;;) {
            gv = __hip_atomic_load(&s_win, __ATOMIC_RELAXED, __HIP_MEMORY_SCOPE_WORKGROUP);
            if ((gv >> 53) == tag) break;
        }

        unsigned widx = 0x1FFFFFu - (unsigned)(gv & 0x1FFFFFull);
        float    wd   = __uint_as_float((unsigned)((gv >> 21) & 0xFFFFFFFFull));

        float uu = (float)(widx % WW);
        float vv = (float)(widx / WW);
        bool val = (wd > 0.1f) && (wd < 2.0f) && __builtin_isfinite(wd);
        px = val ? proj_x(uu, wd) : FINF;
        py = val ? proj_y(vv, wd) : FINF;
        pz = val ? wd : FINF;
    }
}

extern "C" void kernel_launch(void* const* d_in, const int* in_sizes, int n_in,
                              void* d_out, int out_size, void* d_ws, size_t ws_size,
                              hipStream_t stream) {
    const float* depth = (const float*)d_in[0];
    const float* rgb   = (const float*)d_in[1];
    float* out = (float*)d_out;

    // reset the 510 tagged communication words (stale tags from a previous
    // replay could otherwise alias the current run's tags)
    zero_ws_kernel<<<dim3(1), dim3(512), 0, stream>>>();

    void* args[] = { (void*)&depth, (void*)&rgb, (void*)&out };
    hipLaunchCooperativeKernel((const void*)fps_kernel, dim3(NBLK + 1), dim3(NTHR),
                               args, 0, stream);
}